// Round 11
// baseline (168.232 us; speedup 1.0000x reference)
//
#include <hip/hip_runtime.h>

// ---------------------------------------------------------------------------
// Attention block: y = (softmax(scale*(xWq)(xWk)^T) (xWv)) Wout^T
// b=4 n=2048 c=512 h=8 d=64.  bf16 MFMA, fp32 accumulate.
//
// R10:
//   - attn reverted to EXACT R8 (53.0 us proven; R9 dbuf regressed: LDS
//     42.5KB cut occupancy 4->3 blocks/CU, overlap already implicit).
//   - gemm1 fuses the x fp32->bf16 conversion into A-staging (manual
//     float4 loads + RNE pack + ds_write_b128 into the same XOR-chunk
//     layout the DMA produced).  cvt kernel now converts weights only.
//
// Fragment layouts (HW-verified, guide §3):
//   32x32x16: A/B [idx=lane&31][k=(lane>>5)*8+j], C/D: col=lane&31,
//             row=(reg&3)+8*(reg>>2)+4*(lane>>5)
// ---------------------------------------------------------------------------

typedef unsigned short u16;
typedef __attribute__((ext_vector_type(8))) short s16x8;
typedef __attribute__((ext_vector_type(4))) float f32x4;
typedef __attribute__((ext_vector_type(16))) float f32x16;

__device__ __forceinline__ u16 f2bf(float f) {
  unsigned int u = __float_as_uint(f);
  u = (u + 0x7fffu + ((u >> 16) & 1u)) >> 16;   // RNE
  return (u16)u;
}

// async global->LDS, 16 B per lane; lds_base must be wave-uniform
__device__ __forceinline__ void gload16(const u16* g, u16* lds_base) {
  __builtin_amdgcn_global_load_lds(
      (const __attribute__((address_space(1))) unsigned int*)g,
      (__attribute__((address_space(3))) unsigned int*)lds_base, 16, 0, 0);
}

// a[32..63] <-> b[0..31] (VALU pipe, gfx950).  Only safe on distinct values.
__device__ __forceinline__ void permlane32_swap(unsigned& a, unsigned& b) {
  asm volatile("v_permlane32_swap_b32 %0, %1" : "+v"(a), "+v"(b));
}

// ---- fp32 -> bf16 convert for W_qkv, W_out (x is fused into gemm1) --------
__global__ __launch_bounds__(256) void cvt_w(
    const float* __restrict__ w1, const float* __restrict__ w2,
    u16* __restrict__ w1b, u16* __restrict__ w2b) {
  constexpr int N2 = 1536 * 512 / 4, N3 = 512 * 512 / 4;
  int i = blockIdx.x * 256 + threadIdx.x;
  if (i >= N2 + N3) return;
  const float* src;
  u16* dst;
  int j;
  if (i < N2) { src = w1; dst = w1b; j = i; }
  else { src = w2; dst = w2b; j = i - N2; }
  float4 f = ((const float4*)src)[j];
  uint2 o;
  o.x = (unsigned)f2bf(f.x) | ((unsigned)f2bf(f.y) << 16);
  o.y = (unsigned)f2bf(f.z) | ((unsigned)f2bf(f.w) << 16);
  ((uint2*)dst)[j] = o;
}

// ---- GEMM  C[M][N] = A[M][512] * B[N][512]^T  ------------------------------
// MODE 0: A = x in fp32 (converted during staging); Q/K/V epilogue.
// MODE 1: A = bf16 via DMA; fp32 store epilogue.
template <int BN, int MODE>
__global__ __launch_bounds__(256) void gemm128(
    const float* __restrict__ Axf, const u16* __restrict__ A,
    const u16* __restrict__ B, float* __restrict__ Cf,
    u16* __restrict__ Qp, u16* __restrict__ Kp, u16* __restrict__ Vp) {
  constexpr int K = 512;
  constexpr int JN = BN / 32;
  __shared__ u16 smem[128 * 64 + BN * 64];
  u16* As = smem;
  u16* Bs = smem + 128 * 64;
  const int id = blockIdx.x;
  const int bm0 = (id & 63) * 128;        // m-tile -> XCD id&7 = m&7
  const int bn0 = (id >> 6) * BN;
  const int t = threadIdx.x, wave = t >> 6, lane = t & 63;
  const int quad = lane >> 4, l16 = lane & 15;
  const int wm = (wave & 1) * 64, wn = (wave >> 1) * (BN / 2);
  const int lr = lane >> 3, lc = lane & 7;
  const int swz = lc ^ lr;

  f32x4 acc[4][JN] = {};

  for (int k0 = 0; k0 < K; k0 += 64) {
    __syncthreads();
    if constexpr (MODE == 0) {
      // A: fp32 load + RNE pack + ds_write_b128, replicating the DMA
      // layout (slot lc holds global chunk lc^lr of row lr in each group)
#pragma unroll
      for (int a = 0; a < 4; a++) {
        int rl = wave * 32 + a * 8 + lr;
        const float* src = Axf + (size_t)(bm0 + rl) * K + k0 + swz * 8;
        float4 f0 = *(const float4*)src;
        float4 f1 = *(const float4*)(src + 4);
        uint2 p0, p1;
        p0.x = (unsigned)f2bf(f0.x) | ((unsigned)f2bf(f0.y) << 16);
        p0.y = (unsigned)f2bf(f0.z) | ((unsigned)f2bf(f0.w) << 16);
        p1.x = (unsigned)f2bf(f1.x) | ((unsigned)f2bf(f1.y) << 16);
        p1.y = (unsigned)f2bf(f1.z) | ((unsigned)f2bf(f1.w) << 16);
        uint4 pk = { p0.x, p0.y, p1.x, p1.y };
        *(uint4*)(&As[rl * 64 + lc * 8]) = pk;
      }
    } else {
#pragma unroll
      for (int a = 0; a < 4; a++) {
        int r = wave * 32 + a * 8 + lr;
        gload16(A + (size_t)(bm0 + r) * K + k0 + swz * 8,
                &As[(wave * 32 + a * 8) * 64]);
      }
    }
#pragma unroll
    for (int b = 0; b < BN / 32; b++) {
      int r = wave * (BN / 4) + b * 8 + lr;
      gload16(B + (size_t)(bn0 + r) * K + k0 + swz * 8,
              &Bs[(wave * (BN / 4) + b * 8) * 64]);
    }
    __syncthreads();
#pragma unroll
    for (int ks = 0; ks < 2; ks++) {
      s16x8 af[4], bf[JN];
#pragma unroll
      for (int i = 0; i < 4; i++) {
        int m = wm + i * 16 + l16;
        af[i] = *(const s16x8*)(&As[m * 64 + (((ks * 4 + quad) ^ (m & 7)) * 8)]);
      }
#pragma unroll
      for (int j = 0; j < JN; j++) {
        int n = wn + j * 16 + l16;
        bf[j] = *(const s16x8*)(&Bs[n * 64 + (((ks * 4 + quad) ^ (n & 7)) * 8)]);
      }
#pragma unroll
      for (int i = 0; i < 4; i++)
#pragma unroll
        for (int j = 0; j < JN; j++)
          acc[i][j] = __builtin_amdgcn_mfma_f32_16x16x32_bf16(af[i], bf[j], acc[i][j], 0, 0, 0);
    }
  }

  if constexpr (MODE == 1) {
#pragma unroll
    for (int i = 0; i < 4; i++)
#pragma unroll
      for (int j = 0; j < JN; j++)
#pragma unroll
        for (int r = 0; r < 4; r++) {
          int m = bm0 + wm + i * 16 + quad * 4 + r;
          int n = bn0 + wn + j * 16 + l16;
          Cf[(size_t)m * 512 + n] = acc[i][j][r];
        }
  } else {
    const int part = bn0 >> 9;
    if (part < 2) {
      // Q/K: swizzled LDS round-trip -> 8 b128 stores/thread
      const float qs = (part == 0) ? 0.18033688011112042f : 1.0f;  // scale*log2e
      __syncthreads();
#pragma unroll
      for (int i = 0; i < 4; i++)
#pragma unroll
        for (int j = 0; j < JN; j++)
#pragma unroll
          for (int r = 0; r < 4; r++) {
            int row = wm + i * 16 + quad * 4 + r;
            int cn = wn + j * 16 + l16;
            smem[row * 128 + (((cn >> 3) ^ (row & 7)) << 3) + (cn & 7)] =
                f2bf(acc[i][j][r] * qs);
          }
      __syncthreads();
      u16* dst = (part == 0) ? Qp : Kp;
      const int bb = bm0 >> 11;
      const int tokbase = bm0 & 2047;
      const int headbase = (bn0 & 511) >> 6;
#pragma unroll
      for (int it = 0; it < 8; it++) {
        int row = it * 16 + (t >> 4);
        int n0 = (t & 15) * 8;
        s16x8 pk = *(const s16x8*)(&smem[row * 128 + ((((n0 >> 3) ^ (row & 7))) << 3)]);
        int head = headbase + (n0 >> 6), dh = n0 & 63;
        int tok = tokbase + row;
        *(s16x8*)(&dst[((size_t)(bb * 8 + head) * 2048 + tok) * 64 + dh]) = pk;
      }
    } else {
      // V: transpose via LDS, coalesced b128 stores along tok.
      __syncthreads();
#pragma unroll
      for (int i = 0; i < 4; i++)
#pragma unroll
        for (int j = 0; j < JN; j++)
#pragma unroll
          for (int r = 0; r < 4; r++) {
            int row = wm + i * 16 + quad * 4 + r;
            int cn = wn + j * 16 + l16;
            smem[row * 128 + (cn ^ (row & 7))] = f2bf(acc[i][j][r]);
          }
      __syncthreads();
      const int bb = bm0 >> 11;
      const int tokbase = bm0 & 2047;
      const int headbase = (bn0 & 511) >> 6;
#pragma unroll
      for (int it = 0; it < 8; it++) {
        int cn = it * 16 + (t >> 4);
        int dh = cn & 63, head = headbase + (cn >> 6);
        int tok0 = (t & 15) * 8;
        s16x8 pk;
#pragma unroll
        for (int k = 0; k < 8; k++) {
          int row = tok0 + k;
          pk[k] = (short)smem[row * 128 + (cn ^ (row & 7))];
        }
        *(s16x8*)(&Vp[((size_t)(bb * 8 + head) * 64 + dh) * 2048 + tokbase + tok0]) = pk;
      }
    }
  }
}

// ---- attention: EXACT R8 (proven 53.0 us) ---------------------------------
// One block = one (b,h) x 64 Q rows.  K/Vt tiles DMA'd into group-staggered
// LDS (8-row groups @ 520 u16, XOR chunk swizzle).  S^T MFMA, in-register
// P packing, O^T merged via LDS once.  XCD pinning: 4 heads per XCD.
__global__ __launch_bounds__(256) void attn_kernel(
    const u16* __restrict__ Qg, const u16* __restrict__ Kg,
    const u16* __restrict__ Vtg, u16* __restrict__ Og) {
  // Qs padded [64][72]; Ks/Vt staggered: row r at (r>>3)*520 + (r&7)*64
  __shared__ __attribute__((aligned(16))) u16 smem[64 * 72 + 2 * 8 * 520];
  u16* Qs = smem;                  // 4608 u16
  u16* Ks = smem + 64 * 72;        // 4160 u16
  u16* Vt = Ks + 8 * 520;          // 4160 u16
  float* Obuf = (float*)smem;                         // epilogue: [64][68] fp32
  float* Lbuf = (float*)((char*)smem + 64 * 68 * 4);  // [4][64] fp32

  const int id = blockIdx.x;               // 0..1023
  const int xcd = id & 7, slot = id >> 3;  // 128 slots per XCD
  const int bh = xcd * 4 + (slot & 3);
  const int q0 = (slot >> 2) * 64;

  const u16* Qh = Qg + (size_t)bh * 2048 * 64;
  const u16* Kh = Kg + (size_t)bh * 2048 * 64;
  const u16* Vh = Vtg + (size_t)bh * 64 * 2048;
  const int t = threadIdx.x, lane = t & 63, wave = t >> 6;
  const int wq = wave & 1, wk = wave >> 1;   // wq: q-half, wk: kv-half
  const int l32 = lane & 31, half = lane >> 5;
  const int srow = t >> 2, scolb = (t & 3) * 8;
  const int lr = lane >> 3, lc = lane & 7, swz = lc ^ lr;
  const int q = wq * 32 + l32;               // this lane's q row (local)

  // stage Q tile (regular writes, padded), hoist B-operand fragments
#pragma unroll
  for (int p = 0; p < 2; p++) {
    int col = scolb + p * 32;
    *(s16x8*)(&Qs[srow * 72 + col]) = *(const s16x8*)(Qh + (size_t)(q0 + srow) * 64 + col);
  }
  __syncthreads();
  s16x8 bQ[4];
#pragma unroll
  for (int ks = 0; ks < 4; ks++)
    bQ[ks] = *(const s16x8*)(&Qs[q * 72 + ks * 16 + half * 8]);

  f32x16 o[2] = {};   // O^T partial: rows d (regs), cols q (lanes), kv-half wk
  float l_acc = 0.f;

  for (int j0 = 0; j0 < 2048; j0 += 64) {
    __syncthreads();
    // DMA staging: wave handles groups {2w, 2w+1} of K and of Vt
    {
      int g0 = wave * 2, g1 = wave * 2 + 1;
      gload16(Kh + (size_t)(j0 + g0 * 8 + lr) * 64 + swz * 8, &Ks[g0 * 520]);
      gload16(Kh + (size_t)(j0 + g1 * 8 + lr) * 64 + swz * 8, &Ks[g1 * 520]);
      gload16(Vh + (size_t)(g0 * 8 + lr) * 2048 + j0 + swz * 8, &Vt[g0 * 520]);
      gload16(Vh + (size_t)(g1 * 8 + lr) * 2048 + j0 + swz * 8, &Vt[g1 * 520]);
    }
    __syncthreads();

    // S^T block: rows kv = wk*32..+31 (regs), cols q (lanes)
    f32x16 s = {};
    {
      const int rK = wk * 32 + l32;
      const int base = (rK >> 3) * 520 + (rK & 7) * 64;
#pragma unroll
      for (int ks = 0; ks < 4; ks++) {
        s16x8 aK = *(const s16x8*)(&Ks[base + (((ks * 2 + half) ^ (rK & 7)) * 8)]);
        s = __builtin_amdgcn_mfma_f32_32x32x16_bf16(aK, bQ[ks], s, 0, 0, 0);
      }
    }

    // p = 2^s; l in-lane; pack to PV B-frags in registers (distinct data)
    unsigned pu[16];
#pragma unroll
    for (int r = 0; r < 16; r++) {
      float p = __builtin_amdgcn_exp2f(s[r]);
      unsigned u = __float_as_uint(p);
      l_acc += __uint_as_float(u & 0xffff0000u);
      pu[r] = u;
    }
    unsigned g[8];
#pragma unroll
    for (int v = 0; v < 8; v++)
      g[v] = __builtin_amdgcn_perm(pu[2 * v + 1], pu[2 * v], 0x07060302u);
    permlane32_swap(g[0], g[2]);
    permlane32_swap(g[1], g[3]);
    permlane32_swap(g[4], g[6]);
    permlane32_swap(g[5], g[7]);
    s16x8 bP[2];
    ((unsigned*)&bP[0])[0] = g[0]; ((unsigned*)&bP[0])[1] = g[1];
    ((unsigned*)&bP[0])[2] = g[2]; ((unsigned*)&bP[0])[3] = g[3];
    ((unsigned*)&bP[1])[0] = g[4]; ((unsigned*)&bP[1])[1] = g[5];
    ((unsigned*)&bP[1])[2] = g[6]; ((unsigned*)&bP[1])[3] = g[7];

    // O^T += V^T . P^T over this wave's kv half (A=Vt rows d, B=P^T)
#pragma unroll
    for (int dt = 0; dt < 2; dt++) {
      const int rV = dt * 32 + l32;
      const int base = (rV >> 3) * 520 + (rV & 7) * 64;
#pragma unroll
      for (int s2 = 0; s2 < 2; s2++) {
        s16x8 aV = *(const s16x8*)(&Vt[base + (((wk * 4 + s2 * 2 + half) ^ (rV & 7)) * 8)]);
        o[dt] = __builtin_amdgcn_mfma_f32_32x32x16_bf16(aV, bP[s2], o[dt], 0, 0, 0);
      }
    }
  }

  // ---- merge kv-halves (wk pairs), normalize, coalesced store ----
  __syncthreads();   // last tile's frag reads done; smem now reused as Obuf
  Lbuf[(wk * 2 + half) * 64 + q] = l_acc;
  if (wk == 1) {
#pragma unroll
    for (int dt = 0; dt < 2; dt++)
#pragma unroll
      for (int gi = 0; gi < 4; gi++) {
        int d0 = 8 * gi + 4 * half + 32 * dt;
        float4 v = { o[dt][4 * gi + 0], o[dt][4 * gi + 1],
                     o[dt][4 * gi + 2], o[dt][4 * gi + 3] };
        *(float4*)(&Obuf[q * 68 + d0]) = v;
      }
  }
  __syncthreads();
  if (wk == 0) {
    float l = Lbuf[0 * 64 + q] + Lbuf[1 * 64 + q] + Lbuf[2 * 64 + q] + Lbuf[3 * 64 + q];
    float sc = __builtin_amdgcn_rcpf(l);
#pragma unroll
    for (int dt = 0; dt < 2; dt++)
#pragma unroll
      for (int gi = 0; gi < 4; gi++) {
        int d0 = 8 * gi + 4 * half + 32 * dt;
        float4 v = *(float4*)(&Obuf[q * 68 + d0]);
        v.x = (v.x + o[dt][4 * gi + 0]) * sc;
        v.y = (v.y + o[dt][4 * gi + 1]) * sc;
        v.z = (v.z + o[dt][4 * gi + 2]) * sc;
        v.w = (v.w + o[dt][4 * gi + 3]) * sc;
        *(float4*)(&Obuf[q * 68 + d0]) = v;
      }
  }
  __syncthreads();

  // coalesced store: thread t -> (q = t>>2, d0 = (t&3)*16), 32 B per thread
  {
    const int bb = bh >> 3, h = bh & 7;
    int qq = t >> 2, d0 = (t & 3) * 16;
    float f[16];
#pragma unroll
    for (int c = 0; c < 4; c++) {
      float4 v = *(float4*)(&Obuf[qq * 68 + d0 + 4 * c]);
      f[4 * c + 0] = v.x; f[4 * c + 1] = v.y; f[4 * c + 2] = v.z; f[4 * c + 3] = v.w;
    }
    unsigned pk[8];
#pragma unroll
    for (int c = 0; c < 8; c++)
      pk[c] = (unsigned)f2bf(f[2 * c]) | ((unsigned)f2bf(f[2 * c + 1]) << 16);
    size_t base = ((size_t)bb * 2048 + q0 + qq) * 512 + h * 64 + d0;
    uint4 s0 = { pk[0], pk[1], pk[2], pk[3] };
    uint4 s1 = { pk[4], pk[5], pk[6], pk[7] };
    *(uint4*)(&Og[base]) = s0;
    *(uint4*)(&Og[base + 8]) = s1;
  }
}

// ---------------------------------------------------------------------------
extern "C" void kernel_launch(void* const* d_in, const int* in_sizes, int n_in,
                              void* d_out, int out_size, void* d_ws, size_t ws_size,
                              hipStream_t stream) {
  const float* x    = (const float*)d_in[0];   // [4][2048][512]
  const float* Wqkv = (const float*)d_in[1];   // [1536][512]
  const float* Wout = (const float*)d_in[2];   // [512][512]
  float* y = (float*)d_out;                    // [4][2048][512]

  char* ws = (char*)d_ws;
  size_t off = 0;
  auto alloc = [&](size_t bytes) {
    void* p = ws + off;
    off += (bytes + 255) & ~(size_t)255;
    return p;
  };
  u16* wqkvb = (u16*)alloc((size_t)1536 * 512 * 2);
  u16* woutb = (u16*)alloc((size_t)512 * 512 * 2);
  u16* Qw    = (u16*)alloc((size_t)32 * 2048 * 64 * 2);
  u16* Kw    = (u16*)alloc((size_t)32 * 2048 * 64 * 2);
  u16* Vw    = (u16*)alloc((size_t)32 * 2048 * 64 * 2);  // transposed [bh][d][n]
  u16* Ow    = (u16*)alloc((size_t)8192 * 512 * 2);
  if (off > ws_size) return;

  cvt_w<<<1024, 256, 0, stream>>>(Wqkv, Wout, wqkvb, woutb);

  gemm128<128, 0><<<768, 256, 0, stream>>>(x, nullptr, wqkvb, nullptr, Qw, Kw, Vw);
  attn_kernel<<<1024, 256, 0, stream>>>(Qw, Kw, Vw, Ow);
  gemm128<64, 1><<<512, 256, 0, stream>>>(nullptr, Ow, woutb, y, nullptr, nullptr, nullptr);
}

// Round 12
// 149.506 us; speedup vs baseline: 1.1252x; 1.1252x over previous
//
#include <hip/hip_runtime.h>

// ---------------------------------------------------------------------------
// Attention block: y = (softmax(scale*(xWq)(xWk)^T) (xWv)) Wout^T
// b=4 n=2048 c=512 h=8 d=64.  bf16 MFMA, fp32 accumulate.
//
// R11:
//   - cvt reverted to R8 cvt_all (R10 fusion regressed: sync fp32 staging
//     stalls in-loop where DMA didn't).
//   - attn: exact R8 (proven 53.0 us).
//   - GEMMs rebuilt: 64x128 tile, BK=64, DOUBLE-BUFFERED DMA staging with
//     ONE barrier per K-iter.  Rationale: grid==3 blocks/CU (occupancy-
//     capped), K-loop only 8 iters -> the 2x vmcnt(0) drains/iter dominate
//     (gemm ~60us vs ~6us MFMA floor).  Dbuf LDS = 48KiB still fits
//     3 blocks/CU -> no occupancy loss (the R9-attn failure mode).
//
// Fragment layouts (HW-verified, guide §3):
//   16x16x32: A/B [idx=lane&15][k=(lane>>4)*8+j], C/D col=lane&15,
//             row=(lane>>4)*4+reg
//   32x32x16: A/B [idx=lane&31][k=(lane>>5)*8+j], C/D col=lane&31,
//             row=(reg&3)+8*(reg>>2)+4*(lane>>5)
// ---------------------------------------------------------------------------

typedef unsigned short u16;
typedef __attribute__((ext_vector_type(8))) short s16x8;
typedef __attribute__((ext_vector_type(4))) float f32x4;
typedef __attribute__((ext_vector_type(16))) float f32x16;

__device__ __forceinline__ u16 f2bf(float f) {
  unsigned int u = __float_as_uint(f);
  u = (u + 0x7fffu + ((u >> 16) & 1u)) >> 16;   // RNE
  return (u16)u;
}

// async global->LDS, 16 B per lane; lds_base must be wave-uniform
__device__ __forceinline__ void gload16(const u16* g, u16* lds_base) {
  __builtin_amdgcn_global_load_lds(
      (const __attribute__((address_space(1))) unsigned int*)g,
      (__attribute__((address_space(3))) unsigned int*)lds_base, 16, 0, 0);
}

// a[32..63] <-> b[0..31] (VALU pipe, gfx950).  Only safe on distinct values.
__device__ __forceinline__ void permlane32_swap(unsigned& a, unsigned& b) {
  asm volatile("v_permlane32_swap_b32 %0, %1" : "+v"(a), "+v"(b));
}

// ---- fused fp32 -> bf16 convert for x, W_qkv, W_out (R8 version) ----------
__global__ __launch_bounds__(256) void cvt_all(
    const float* __restrict__ x, const float* __restrict__ w1,
    const float* __restrict__ w2, u16* __restrict__ xb,
    u16* __restrict__ w1b, u16* __restrict__ w2b) {
  constexpr int N1 = 8192 * 512 / 4, N2 = 1536 * 512 / 4, N3 = 512 * 512 / 4;
  int i = blockIdx.x * 256 + threadIdx.x;
  if (i >= N1 + N2 + N3) return;
  const float* src;
  u16* dst;
  int j;
  if (i < N1) { src = x; dst = xb; j = i; }
  else if (i < N1 + N2) { src = w1; dst = w1b; j = i - N1; }
  else { src = w2; dst = w2b; j = i - N1 - N2; }
  float4 f = ((const float4*)src)[j];
  uint2 o;
  o.x = (unsigned)f2bf(f.x) | ((unsigned)f2bf(f.y) << 16);
  o.y = (unsigned)f2bf(f.z) | ((unsigned)f2bf(f.w) << 16);
  ((uint2*)dst)[j] = o;
}

// ---- GEMM  C[M][N] = A[M][512] * B[N][512]^T  (64x128 tile, dbuf) ---------
// 1-D grid, m-major (id & (MT-1)) -> XCD pinned by m.  One barrier/K-iter.
// MODE 0: Q(*scale*log2e)/K via swizzled-LDS epilogue, V via LDS transpose.
// MODE 1: fp32 store (ldc=512).
template <int MODE>
__global__ __launch_bounds__(256) void gemm_db(
    const u16* __restrict__ A, const u16* __restrict__ B,
    float* __restrict__ Cf,
    u16* __restrict__ Qp, u16* __restrict__ Kp, u16* __restrict__ Vp) {
  constexpr int K = 512;
  constexpr int BUF = (64 + 128) * 64;            // u16 per buffer (24 KiB)
  __shared__ u16 smem[2 * BUF];                   // 48 KiB -> 3 blocks/CU
  const int id = blockIdx.x;
  const int bm0 = (id & 127) * 64;                // m-tile -> XCD id&7
  const int bn0 = (id >> 7) * 128;
  const int t = threadIdx.x, wave = t >> 6, lane = t & 63;
  const int quad = lane >> 4, l16 = lane & 15;
  const int wm = (wave & 1) * 32, wn = (wave >> 1) * 64;
  const int lr = lane >> 3, lc = lane & 7;
  const int swz = lc ^ lr;

  f32x4 acc[2][4] = {};

  // issue DMAs for K-slice kt into buffer buf
  auto stage = [&](int buf, int kt) {
    u16* As = smem + buf * BUF;
    u16* Bs = As + 64 * 64;
    const int k0 = kt * 64;
#pragma unroll
    for (int a = 0; a < 2; a++) {
      int g = wave * 2 + a;                       // A group (8 rows)
      gload16(A + (size_t)(bm0 + g * 8 + lr) * K + k0 + swz * 8, &As[g * 8 * 64]);
    }
#pragma unroll
    for (int b = 0; b < 4; b++) {
      int g = wave * 4 + b;                       // B group
      gload16(B + (size_t)(bn0 + g * 8 + lr) * K + k0 + swz * 8, &Bs[g * 8 * 64]);
    }
  };

  stage(0, 0);
  __syncthreads();

  for (int kt = 0; kt < 8; kt++) {
    const u16* As = smem + (kt & 1) * BUF;
    const u16* Bs = As + 64 * 64;
    if (kt < 7) stage((kt + 1) & 1, kt + 1);      // overlaps compute below
#pragma unroll
    for (int ks = 0; ks < 2; ks++) {
      s16x8 af[2], bf[4];
#pragma unroll
      for (int i = 0; i < 2; i++) {
        int m = wm + i * 16 + l16;
        af[i] = *(const s16x8*)(&As[m * 64 + (((ks * 4 + quad) ^ (m & 7)) * 8)]);
      }
#pragma unroll
      for (int j = 0; j < 4; j++) {
        int n = wn + j * 16 + l16;
        bf[j] = *(const s16x8*)(&Bs[n * 64 + (((ks * 4 + quad) ^ (n & 7)) * 8)]);
      }
#pragma unroll
      for (int i = 0; i < 2; i++)
#pragma unroll
        for (int j = 0; j < 4; j++)
          acc[i][j] = __builtin_amdgcn_mfma_f32_16x16x32_bf16(af[i], bf[j], acc[i][j], 0, 0, 0);
    }
    __syncthreads();   // drains next-tile DMA (overlapped) + guards buf reuse
  }

  if constexpr (MODE == 1) {
#pragma unroll
    for (int i = 0; i < 2; i++)
#pragma unroll
      for (int j = 0; j < 4; j++)
#pragma unroll
        for (int r = 0; r < 4; r++) {
          int m = bm0 + wm + i * 16 + quad * 4 + r;
          int n = bn0 + wn + j * 16 + l16;
          Cf[(size_t)m * 512 + n] = acc[i][j][r];
        }
  } else {
    const int part = bn0 >> 9;                    // uniform per block
    const int bb = bm0 >> 11;
    const int tokbase = bm0 & 2047;
    const int headbase = (bn0 & 511) >> 6;
    if (part < 2) {
      // Q/K: swizzled LDS round-trip -> b128 stores
      const float qs = (part == 0) ? 0.18033688011112042f : 1.0f;  // scale*log2e
#pragma unroll
      for (int i = 0; i < 2; i++)
#pragma unroll
        for (int j = 0; j < 4; j++)
#pragma unroll
          for (int r = 0; r < 4; r++) {
            int row = wm + i * 16 + quad * 4 + r;
            int cn = wn + j * 16 + l16;
            smem[row * 128 + (((cn >> 3) ^ (row & 7)) << 3) + (cn & 7)] =
                f2bf(acc[i][j][r] * qs);
          }
      __syncthreads();
      u16* dst = (part == 0) ? Qp : Kp;
#pragma unroll
      for (int it = 0; it < 4; it++) {
        int row = it * 16 + (t >> 4);
        int n0 = (t & 15) * 8;
        s16x8 pk = *(const s16x8*)(&smem[row * 128 + ((((n0 >> 3) ^ (row & 7))) << 3)]);
        int head = headbase + (n0 >> 6), dh = n0 & 63;
        int tok = tokbase + row;
        *(s16x8*)(&dst[((size_t)(bb * 8 + head) * 2048 + tok) * 64 + dh]) = pk;
      }
    } else {
      // V: transpose via LDS, coalesced b128 stores along tok.
#pragma unroll
      for (int i = 0; i < 2; i++)
#pragma unroll
        for (int j = 0; j < 4; j++)
#pragma unroll
          for (int r = 0; r < 4; r++) {
            int row = wm + i * 16 + quad * 4 + r;
            int cn = wn + j * 16 + l16;
            smem[row * 128 + (cn ^ (row & 7))] = f2bf(acc[i][j][r]);
          }
      __syncthreads();
#pragma unroll
      for (int it = 0; it < 4; it++) {
        int cn = it * 32 + (t >> 3);
        int dh = cn & 63, head = headbase + (cn >> 6);
        int tok0 = (t & 7) * 8;
        s16x8 pk;
#pragma unroll
        for (int k = 0; k < 8; k++) {
          int row = tok0 + k;
          pk[k] = (short)smem[row * 128 + (cn ^ (row & 7))];
        }
        *(s16x8*)(&Vp[((size_t)(bb * 8 + head) * 64 + dh) * 2048 + tokbase + tok0]) = pk;
      }
    }
  }
}

// ---- attention: EXACT R8 (proven 53.0 us) ---------------------------------
__global__ __launch_bounds__(256) void attn_kernel(
    const u16* __restrict__ Qg, const u16* __restrict__ Kg,
    const u16* __restrict__ Vtg, u16* __restrict__ Og) {
  __shared__ __attribute__((aligned(16))) u16 smem[64 * 72 + 2 * 8 * 520];
  u16* Qs = smem;                  // 4608 u16
  u16* Ks = smem + 64 * 72;        // 4160 u16
  u16* Vt = Ks + 8 * 520;          // 4160 u16
  float* Obuf = (float*)smem;                         // epilogue: [64][68] fp32
  float* Lbuf = (float*)((char*)smem + 64 * 68 * 4);  // [4][64] fp32

  const int id = blockIdx.x;               // 0..1023
  const int xcd = id & 7, slot = id >> 3;  // 128 slots per XCD
  const int bh = xcd * 4 + (slot & 3);
  const int q0 = (slot >> 2) * 64;

  const u16* Qh = Qg + (size_t)bh * 2048 * 64;
  const u16* Kh = Kg + (size_t)bh * 2048 * 64;
  const u16* Vh = Vtg + (size_t)bh * 64 * 2048;
  const int t = threadIdx.x, lane = t & 63, wave = t >> 6;
  const int wq = wave & 1, wk = wave >> 1;
  const int l32 = lane & 31, half = lane >> 5;
  const int srow = t >> 2, scolb = (t & 3) * 8;
  const int lr = lane >> 3, lc = lane & 7, swz = lc ^ lr;
  const int q = wq * 32 + l32;

#pragma unroll
  for (int p = 0; p < 2; p++) {
    int col = scolb + p * 32;
    *(s16x8*)(&Qs[srow * 72 + col]) = *(const s16x8*)(Qh + (size_t)(q0 + srow) * 64 + col);
  }
  __syncthreads();
  s16x8 bQ[4];
#pragma unroll
  for (int ks = 0; ks < 4; ks++)
    bQ[ks] = *(const s16x8*)(&Qs[q * 72 + ks * 16 + half * 8]);

  f32x16 o[2] = {};
  float l_acc = 0.f;

  for (int j0 = 0; j0 < 2048; j0 += 64) {
    __syncthreads();
    {
      int g0 = wave * 2, g1 = wave * 2 + 1;
      gload16(Kh + (size_t)(j0 + g0 * 8 + lr) * 64 + swz * 8, &Ks[g0 * 520]);
      gload16(Kh + (size_t)(j0 + g1 * 8 + lr) * 64 + swz * 8, &Ks[g1 * 520]);
      gload16(Vh + (size_t)(g0 * 8 + lr) * 2048 + j0 + swz * 8, &Vt[g0 * 520]);
      gload16(Vh + (size_t)(g1 * 8 + lr) * 2048 + j0 + swz * 8, &Vt[g1 * 520]);
    }
    __syncthreads();

    f32x16 s = {};
    {
      const int rK = wk * 32 + l32;
      const int base = (rK >> 3) * 520 + (rK & 7) * 64;
#pragma unroll
      for (int ks = 0; ks < 4; ks++) {
        s16x8 aK = *(const s16x8*)(&Ks[base + (((ks * 2 + half) ^ (rK & 7)) * 8)]);
        s = __builtin_amdgcn_mfma_f32_32x32x16_bf16(aK, bQ[ks], s, 0, 0, 0);
      }
    }

    unsigned pu[16];
#pragma unroll
    for (int r = 0; r < 16; r++) {
      float p = __builtin_amdgcn_exp2f(s[r]);
      unsigned u = __float_as_uint(p);
      l_acc += __uint_as_float(u & 0xffff0000u);
      pu[r] = u;
    }
    unsigned g[8];
#pragma unroll
    for (int v = 0; v < 8; v++)
      g[v] = __builtin_amdgcn_perm(pu[2 * v + 1], pu[2 * v], 0x07060302u);
    permlane32_swap(g[0], g[2]);
    permlane32_swap(g[1], g[3]);
    permlane32_swap(g[4], g[6]);
    permlane32_swap(g[5], g[7]);
    s16x8 bP[2];
    ((unsigned*)&bP[0])[0] = g[0]; ((unsigned*)&bP[0])[1] = g[1];
    ((unsigned*)&bP[0])[2] = g[2]; ((unsigned*)&bP[0])[3] = g[3];
    ((unsigned*)&bP[1])[0] = g[4]; ((unsigned*)&bP[1])[1] = g[5];
    ((unsigned*)&bP[1])[2] = g[6]; ((unsigned*)&bP[1])[3] = g[7];

#pragma unroll
    for (int dt = 0; dt < 2; dt++) {
      const int rV = dt * 32 + l32;
      const int base = (rV >> 3) * 520 + (rV & 7) * 64;
#pragma unroll
      for (int s2 = 0; s2 < 2; s2++) {
        s16x8 aV = *(const s16x8*)(&Vt[base + (((wk * 4 + s2 * 2 + half) ^ (rV & 7)) * 8)]);
        o[dt] = __builtin_amdgcn_mfma_f32_32x32x16_bf16(aV, bP[s2], o[dt], 0, 0, 0);
      }
    }
  }

  __syncthreads();
  Lbuf[(wk * 2 + half) * 64 + q] = l_acc;
  if (wk == 1) {
#pragma unroll
    for (int dt = 0; dt < 2; dt++)
#pragma unroll
      for (int gi = 0; gi < 4; gi++) {
        int d0 = 8 * gi + 4 * half + 32 * dt;
        float4 v = { o[dt][4 * gi + 0], o[dt][4 * gi + 1],
                     o[dt][4 * gi + 2], o[dt][4 * gi + 3] };
        *(float4*)(&Obuf[q * 68 + d0]) = v;
      }
  }
  __syncthreads();
  if (wk == 0) {
    float l = Lbuf[0 * 64 + q] + Lbuf[1 * 64 + q] + Lbuf[2 * 64 + q] + Lbuf[3 * 64 + q];
    float sc = __builtin_amdgcn_rcpf(l);
#pragma unroll
    for (int dt = 0; dt < 2; dt++)
#pragma unroll
      for (int gi = 0; gi < 4; gi++) {
        int d0 = 8 * gi + 4 * half + 32 * dt;
        float4 v = *(float4*)(&Obuf[q * 68 + d0]);
        v.x = (v.x + o[dt][4 * gi + 0]) * sc;
        v.y = (v.y + o[dt][4 * gi + 1]) * sc;
        v.z = (v.z + o[dt][4 * gi + 2]) * sc;
        v.w = (v.w + o[dt][4 * gi + 3]) * sc;
        *(float4*)(&Obuf[q * 68 + d0]) = v;
      }
  }
  __syncthreads();

  {
    const int bb = bh >> 3, h = bh & 7;
    int qq = t >> 2, d0 = (t & 3) * 16;
    float f[16];
#pragma unroll
    for (int c = 0; c < 4; c++) {
      float4 v = *(float4*)(&Obuf[qq * 68 + d0 + 4 * c]);
      f[4 * c + 0] = v.x; f[4 * c + 1] = v.y; f[4 * c + 2] = v.z; f[4 * c + 3] = v.w;
    }
    unsigned pk[8];
#pragma unroll
    for (int c = 0; c < 8; c++)
      pk[c] = (unsigned)f2bf(f[2 * c]) | ((unsigned)f2bf(f[2 * c + 1]) << 16);
    size_t base = ((size_t)bb * 2048 + q0 + qq) * 512 + h * 64 + d0;
    uint4 s0 = { pk[0], pk[1], pk[2], pk[3] };
    uint4 s1 = { pk[4], pk[5], pk[6], pk[7] };
    *(uint4*)(&Og[base]) = s0;
    *(uint4*)(&Og[base + 8]) = s1;
  }
}

// ---------------------------------------------------------------------------
extern "C" void kernel_launch(void* const* d_in, const int* in_sizes, int n_in,
                              void* d_out, int out_size, void* d_ws, size_t ws_size,
                              hipStream_t stream) {
  const float* x    = (const float*)d_in[0];   // [4][2048][512]
  const float* Wqkv = (const float*)d_in[1];   // [1536][512]
  const float* Wout = (const float*)d_in[2];   // [512][512]
  float* y = (float*)d_out;                    // [4][2048][512]

  char* ws = (char*)d_ws;
  size_t off = 0;
  auto alloc = [&](size_t bytes) {
    void* p = ws + off;
    off += (bytes + 255) & ~(size_t)255;
    return p;
  };
  u16* xb    = (u16*)alloc((size_t)8192 * 512 * 2);
  u16* wqkvb = (u16*)alloc((size_t)1536 * 512 * 2);
  u16* woutb = (u16*)alloc((size_t)512 * 512 * 2);
  u16* Qw    = (u16*)alloc((size_t)32 * 2048 * 64 * 2);
  u16* Kw    = (u16*)alloc((size_t)32 * 2048 * 64 * 2);
  u16* Vw    = (u16*)alloc((size_t)32 * 2048 * 64 * 2);  // transposed [bh][d][n]
  u16* Ow    = (u16*)alloc((size_t)8192 * 512 * 2);
  if (off > ws_size) return;

  cvt_all<<<5120, 256, 0, stream>>>(x, Wqkv, Wout, xb, wqkvb, woutb);

  gemm_db<0><<<1536, 256, 0, stream>>>(xb, wqkvb, nullptr, Qw, Kw, Vw);
  attn_kernel<<<1024, 256, 0, stream>>>(Qw, Kw, Vw, Ow);
  gemm_db<1><<<512, 256, 0, stream>>>(Ow, woutb, y, nullptr, nullptr, nullptr);
}